// Round 1
// baseline (862.548 us; speedup 1.0000x reference)
//
#include <hip/hip_runtime.h>

#define BATCH 16
#define CCH 512
#define LEN 4096

typedef unsigned short u16;
typedef __bf16 bf16x8 __attribute__((ext_vector_type(8)));
typedef float f32x4 __attribute__((ext_vector_type(4)));
typedef u16 u16x8 __attribute__((ext_vector_type(8)));
typedef u16 u16x4 __attribute__((ext_vector_type(4)));

__device__ __forceinline__ u16 f2bf(float f) {
    unsigned u = __float_as_uint(f);
    u = (u + 0x7fffu + ((u >> 16) & 1u)) >> 16;
    return (u16)u;
}
__device__ __forceinline__ float bf2f(u16 v) {
    return __uint_as_float(((unsigned)v) << 16);
}
__device__ __forceinline__ float silu_f(float v) {
    return v / (1.f + __expf(-v));
}

// ---------------------------------------------------------------------------
// Scale reduction: partial |w| sums for w1 and w2 (deterministic tree).
// grid 256, block 256. Each block covers 3072 elements of each weight tensor.
__global__ __launch_bounds__(256)
void absmean_partial(const float* __restrict__ w1, const float* __restrict__ w2,
                     float* __restrict__ part) {
    const int tid = threadIdx.x;
    const int base = blockIdx.x * 3072;
    float s1 = 0.f, s2 = 0.f;
    for (int i = tid; i < 3072; i += 256) {
        s1 += fabsf(w1[base + i]);
        s2 += fabsf(w2[base + i]);
    }
    __shared__ float r1[256], r2[256];
    r1[tid] = s1; r2[tid] = s2;
    __syncthreads();
    for (int off = 128; off > 0; off >>= 1) {
        if (tid < off) { r1[tid] += r1[tid + off]; r2[tid] += r2[tid + off]; }
        __syncthreads();
    }
    if (tid == 0) { part[blockIdx.x] = r1[0]; part[256 + blockIdx.x] = r2[0]; }
}

__global__ __launch_bounds__(256)
void finalize_scale(const float* __restrict__ part, float* __restrict__ sv) {
    const int tid = threadIdx.x;
    __shared__ float r1[256], r2[256];
    r1[tid] = part[tid]; r2[tid] = part[256 + tid];
    __syncthreads();
    for (int off = 128; off > 0; off >>= 1) {
        if (tid < off) { r1[tid] += r1[tid + off]; r2[tid] += r2[tid + off]; }
        __syncthreads();
    }
    if (tid == 0) {
        sv[0] = fmaxf(r1[0] * (1.f / 786432.f), 1e-5f);
        sv[1] = fmaxf(r2[0] * (1.f / 786432.f), 1e-5f);
    }
}

// ---------------------------------------------------------------------------
// Quantize w[o][i][k] -> wq_t[k][o][i] as exact bf16 ternary {-1,0,+1}.
// grid 3072, block 256 (one thread per element).
__global__ __launch_bounds__(256)
void quantize_w(const float* __restrict__ w, const float* __restrict__ sv,
                int sidx, u16* __restrict__ wqt) {
    const int idx = blockIdx.x * 256 + threadIdx.x;   // [0, 786432)
    const float s = sv[sidx];
    float q = rintf(w[idx] / s);                       // round-half-even like jnp.round
    q = fmaxf(-1.f, fminf(1.f, q));
    const int o   = idx / 1536;
    const int rem = idx - o * 1536;
    const int i   = rem / 3;
    const int k   = rem - i * 3;
    wqt[k * (CCH * CCH) + o * CCH + i] = f2bf(q);      // exact for -1/0/1
}

// ---------------------------------------------------------------------------
// RMSNorm (channel axis) + gain + SiLU + transpose to h_t[b][l][i] (bf16).
// grid 16*128 = 2048, block 256.  Tile: 32 l x 512 i held as bf16 in LDS.
__global__ __launch_bounds__(256)
void rms_silu_transpose(const float* __restrict__ x, const float* __restrict__ g,
                        u16* __restrict__ h_t) {
    __shared__ u16   xt[CCH][33];   // bf16 tile, padded
    __shared__ float red[8][32];
    __shared__ float rinv[32];
    const int tid = threadIdx.x;
    const int bb  = blockIdx.x >> 7;
    const int l0  = (blockIdx.x & 127) << 5;

    const size_t xbase = (size_t)bb * CCH * LEN + l0;
    {
        const int i_hi = tid >> 3;          // 0..31
        const int l4   = (tid & 7) << 2;    // 0,4,...,28
        #pragma unroll
        for (int it = 0; it < 16; ++it) {
            const int i = it * 32 + i_hi;
            const float4 v = *(const float4*)&x[xbase + (size_t)i * LEN + l4];
            xt[i][l4 + 0] = f2bf(v.x);
            xt[i][l4 + 1] = f2bf(v.y);
            xt[i][l4 + 2] = f2bf(v.z);
            xt[i][l4 + 3] = f2bf(v.w);
        }
    }
    __syncthreads();
    {
        const int l = tid & 31, seg = tid >> 5;
        const int ibeg = seg * 64;
        float ss = 0.f;
        #pragma unroll 8
        for (int i = ibeg; i < ibeg + 64; ++i) {
            const float v = bf2f(xt[i][l]);
            ss += v * v;
        }
        red[seg][l] = ss;
    }
    __syncthreads();
    if (tid < 32) {
        float tot = 0.f;
        #pragma unroll
        for (int k2 = 0; k2 < 8; ++k2) tot += red[k2][tid];
        rinv[tid] = rsqrtf(tot * (1.f / 512.f) + 1e-6f);
    }
    __syncthreads();
    {
        const int l  = tid >> 3;            // 0..31
        const int i0 = (tid & 7) << 6;      // 0,64,...,448
        const float ri = rinv[l];
        const size_t ob = ((size_t)bb * LEN + l0 + l) * CCH + i0;
        for (int ii = 0; ii < 64; ii += 8) {
            u16x8 ov;
            #pragma unroll
            for (int jj = 0; jj < 8; ++jj) {
                const int i = i0 + ii + jj;
                float v = bf2f(xt[i][l]) * ri * g[i];
                ov[jj] = f2bf(silu_f(v));
            }
            *(u16x8*)&h_t[ob + ii] = ov;
        }
    }
}

// ---------------------------------------------------------------------------
// Conv-as-GEMM with MFMA 16x16x32 bf16.
//   out[o, (b,l)] = sum_{k,i} Wq[k][o][i] * Bsrc[b][l+k-1][i]
// M=512 (o), N=65536 (b,l), Kgemm = 3 shifts x 512.
// 128x128 tile / block, 4 waves (2x2), per-wave 64x64 (4x4 fragments).
// BK=64, single LDS buffer, 2-phase with register prefetch of next K-step.
// EPI=1: h1 = silu(s*acc + bias) -> bf16 [b][l][o].
// EPI=2: out = s*acc + bias + residual -> fp32 [b][o][l].
template<int EPI>
__global__ __launch_bounds__(256)
void conv_gemm(const u16* __restrict__ Bsrc, const u16* __restrict__ Wq,
               const float* __restrict__ sptr, const float* __restrict__ bias,
               const float* __restrict__ resid, u16* __restrict__ outb,
               float* __restrict__ outf) {
    __shared__ u16 lA[128 * 64];
    __shared__ u16 lB[128 * 64];
    const int tid  = threadIdx.x;
    const int lane = tid & 63;
    const int wave = tid >> 6;
    const int wr = wave >> 1, wc = wave & 1;
    const int mt = blockIdx.x & 3;       // consecutive blocks share the B-panel
    const int nt = blockIdx.x >> 2;
    const int o0 = mt << 7;
    const int bb = nt >> 5;
    const int l0 = (nt & 31) << 7;

    const int r0 = tid >> 3;             // staging row within 32-row group
    const int cc = (tid & 7) << 3;       // staging column offset (ushorts)

    uint4 rA[4], rB[4];
    auto loadstep = [&](int s) {
        const int ks = s >> 3;
        const int i0 = (s & 7) << 6;
        const u16* wbase = Wq + ks * (CCH * CCH) + i0 + cc;
        const u16* hbase = Bsrc + (size_t)bb * LEN * CCH + i0 + cc;
        #pragma unroll
        for (int it = 0; it < 4; ++it) {
            const int row = it * 32 + r0;
            rA[it] = *(const uint4*)(wbase + (o0 + row) * CCH);
            const int lsrc = l0 + row + ks - 1;
            if ((unsigned)lsrc < (unsigned)LEN)
                rB[it] = *(const uint4*)(hbase + (size_t)lsrc * CCH);
            else
                rB[it] = make_uint4(0u, 0u, 0u, 0u);
        }
    };

    const f32x4 zero4 = {0.f, 0.f, 0.f, 0.f};
    f32x4 acc[4][4];
    #pragma unroll
    for (int m = 0; m < 4; ++m)
        #pragma unroll
        for (int n = 0; n < 4; ++n)
            acc[m][n] = zero4;

    loadstep(0);

    const int ldsw = tid << 3;  // (it*256+tid)*8 = it*2048 + ldsw
    const int rba = (wr * 64 + (lane & 15)) * 64 + ((lane >> 4) << 3);
    const int rbb = (wc * 64 + (lane & 15)) * 64 + ((lane >> 4) << 3);

    for (int s = 0; s < 24; ++s) {
        __syncthreads();
        #pragma unroll
        for (int it = 0; it < 4; ++it) {
            *(uint4*)&lA[it * 2048 + ldsw] = rA[it];
            *(uint4*)&lB[it * 2048 + ldsw] = rB[it];
        }
        __syncthreads();
        if (s < 23) loadstep(s + 1);   // overlap next-step global loads with MFMAs
        #pragma unroll
        for (int kk = 0; kk < 2; ++kk) {
            bf16x8 av[4], bv[4];
            #pragma unroll
            for (int m = 0; m < 4; ++m)
                av[m] = *(const bf16x8*)&lA[rba + m * 1024 + kk * 32];
            #pragma unroll
            for (int n = 0; n < 4; ++n)
                bv[n] = *(const bf16x8*)&lB[rbb + n * 1024 + kk * 32];
            #pragma unroll
            for (int m = 0; m < 4; ++m)
                #pragma unroll
                for (int n = 0; n < 4; ++n)
                    acc[m][n] = __builtin_amdgcn_mfma_f32_16x16x32_bf16(
                        av[m], bv[n], acc[m][n], 0, 0, 0);
        }
    }

    const float sc = sptr[0];
    const int lbase = l0 + wc * 64 + (lane & 15);
    const int obase = o0 + wr * 64 + ((lane >> 4) << 2);

    if (EPI == 1) {
        #pragma unroll
        for (int m = 0; m < 4; ++m) {
            const int ob = obase + m * 16;
            const float bz0 = bias[ob + 0], bz1 = bias[ob + 1];
            const float bz2 = bias[ob + 2], bz3 = bias[ob + 3];
            #pragma unroll
            for (int n = 0; n < 4; ++n) {
                const int l = lbase + n * 16;
                const f32x4 a = acc[m][n];
                u16x4 ov;
                ov[0] = f2bf(silu_f(sc * a[0] + bz0));
                ov[1] = f2bf(silu_f(sc * a[1] + bz1));
                ov[2] = f2bf(silu_f(sc * a[2] + bz2));
                ov[3] = f2bf(silu_f(sc * a[3] + bz3));
                *(u16x4*)&outb[((size_t)bb * LEN + l) * CCH + ob] = ov;
            }
        }
    } else {
        #pragma unroll
        for (int m = 0; m < 4; ++m) {
            const int ob = obase + m * 16;
            #pragma unroll
            for (int n = 0; n < 4; ++n) {
                const int l = lbase + n * 16;
                const f32x4 a = acc[m][n];
                #pragma unroll
                for (int j = 0; j < 4; ++j) {
                    const size_t idx = ((size_t)bb * CCH + (ob + j)) * LEN + l;
                    outf[idx] = sc * a[j] + bias[ob + j] + resid[idx];
                }
            }
        }
    }
}

// ---------------------------------------------------------------------------
extern "C" void kernel_launch(void* const* d_in, const int* in_sizes, int n_in,
                              void* d_out, int out_size, void* d_ws, size_t ws_size,
                              hipStream_t stream) {
    const float* x  = (const float*)d_in[0];
    const float* w1 = (const float*)d_in[1];
    const float* b1 = (const float*)d_in[2];
    const float* w2 = (const float*)d_in[3];
    const float* b2 = (const float*)d_in[4];
    const float* g  = (const float*)d_in[5];
    float* out = (float*)d_out;

    char* ws = (char*)d_ws;
    float* sv   = (float*)ws;                                  // 2 floats
    float* part = (float*)(ws + 256);                          // 512 floats
    u16* wq1  = (u16*)(ws + 4096);                             // 3*512*512 bf16
    u16* wq2  = (u16*)(ws + 4096 + 1572864);
    u16* h_t  = (u16*)(ws + 4096 + 2 * 1572864);               // [16][4096][512] bf16
    u16* h1_t = (u16*)(ws + 4096 + 2 * 1572864 + 67108864);    // [16][4096][512] bf16
    // total ws use: ~137.4 MB

    absmean_partial<<<dim3(256), dim3(256), 0, stream>>>(w1, w2, part);
    finalize_scale<<<dim3(1), dim3(256), 0, stream>>>(part, sv);
    quantize_w<<<dim3(3072), dim3(256), 0, stream>>>(w1, sv, 0, wq1);
    quantize_w<<<dim3(3072), dim3(256), 0, stream>>>(w2, sv, 1, wq2);
    rms_silu_transpose<<<dim3(2048), dim3(256), 0, stream>>>(x, g, h_t);
    conv_gemm<1><<<dim3(2048), dim3(256), 0, stream>>>(h_t, wq1, sv, b1, nullptr,
                                                       h1_t, nullptr);
    conv_gemm<2><<<dim3(2048), dim3(256), 0, stream>>>(h1_t, wq2, sv + 1, b2, x,
                                                       nullptr, out);
}

// Round 2
// 440.847 us; speedup vs baseline: 1.9566x; 1.9566x over previous
//
#include <hip/hip_runtime.h>

#define BATCH 16
#define CCH 512
#define LEN 4096
#define LPAD 4098

typedef unsigned short u16;
typedef __bf16 bf16x8 __attribute__((ext_vector_type(8)));
typedef float f32x4 __attribute__((ext_vector_type(4)));
typedef u16 u16x8 __attribute__((ext_vector_type(8)));
typedef u16 u16x4 __attribute__((ext_vector_type(4)));

__device__ __forceinline__ u16 f2bf(float f) {
    unsigned u = __float_as_uint(f);
    u = (u + 0x7fffu + ((u >> 16) & 1u)) >> 16;
    return (u16)u;
}
__device__ __forceinline__ float bf2f(u16 v) {
    return __uint_as_float(((unsigned)v) << 16);
}
__device__ __forceinline__ float silu_f(float v) {
    return v / (1.f + __expf(-v));
}
// async 16B/lane global->LDS (wave-uniform LDS base + lane*16)
__device__ __forceinline__ void async16(const u16* g, u16* l) {
    __builtin_amdgcn_global_load_lds(
        (const __attribute__((address_space(1))) unsigned int*)g,
        (__attribute__((address_space(3))) unsigned int*)l, 16, 0, 0);
}

// ---------------------------------------------------------------------------
__global__ __launch_bounds__(256)
void absmean_partial(const float* __restrict__ w1, const float* __restrict__ w2,
                     float* __restrict__ part) {
    const int tid = threadIdx.x;
    const int base = blockIdx.x * 3072;
    float s1 = 0.f, s2 = 0.f;
    for (int i = tid; i < 3072; i += 256) {
        s1 += fabsf(w1[base + i]);
        s2 += fabsf(w2[base + i]);
    }
    __shared__ float r1[256], r2[256];
    r1[tid] = s1; r2[tid] = s2;
    __syncthreads();
    for (int off = 128; off > 0; off >>= 1) {
        if (tid < off) { r1[tid] += r1[tid + off]; r2[tid] += r2[tid + off]; }
        __syncthreads();
    }
    if (tid == 0) { part[blockIdx.x] = r1[0]; part[256 + blockIdx.x] = r2[0]; }
}

__global__ __launch_bounds__(256)
void finalize_scale(const float* __restrict__ part, float* __restrict__ sv) {
    const int tid = threadIdx.x;
    __shared__ float r1[256], r2[256];
    r1[tid] = part[tid]; r2[tid] = part[256 + tid];
    __syncthreads();
    for (int off = 128; off > 0; off >>= 1) {
        if (tid < off) { r1[tid] += r1[tid + off]; r2[tid] += r2[tid + off]; }
        __syncthreads();
    }
    if (tid == 0) {
        sv[0] = fmaxf(r1[0] * (1.f / 786432.f), 1e-5f);
        sv[1] = fmaxf(r2[0] * (1.f / 786432.f), 1e-5f);
    }
}

// ---------------------------------------------------------------------------
// Quantize w[o][i][k] -> wq_t[k][o][i] as exact bf16 ternary {-1,0,+1}.
__global__ __launch_bounds__(256)
void quantize_w(const float* __restrict__ w, const float* __restrict__ sv,
                int sidx, u16* __restrict__ wqt) {
    const int idx = blockIdx.x * 256 + threadIdx.x;
    const float s = sv[sidx];
    float q = rintf(w[idx] / s);
    q = fmaxf(-1.f, fminf(1.f, q));
    const int o   = idx / 1536;
    const int rem = idx - o * 1536;
    const int i   = rem / 3;
    const int k   = rem - i * 3;
    wqt[k * (CCH * CCH) + o * CCH + i] = f2bf(q);
}

// zero the padded boundary rows (l=-1 and l=4096) of both activation buffers
__global__ __launch_bounds__(256)
void zero_pads(u16* __restrict__ h, u16* __restrict__ h1) {
    const int idx = blockIdx.x * 256 + threadIdx.x;   // [0, 16384)
    const int b = idx >> 10;
    const int r = (idx >> 9) & 1;
    const int i = idx & 511;
    const size_t off = ((size_t)b * LPAD + (r ? (LPAD - 1) : 0)) * CCH + i;
    h[off] = 0;
    h1[off] = 0;
}

// ---------------------------------------------------------------------------
// RMSNorm + gain + SiLU + transpose to h_pad[b][l+1][i] (bf16).
__global__ __launch_bounds__(256)
void rms_silu_transpose(const float* __restrict__ x, const float* __restrict__ g,
                        u16* __restrict__ h_t) {
    __shared__ u16   xt[CCH][33];
    __shared__ float red[8][32];
    __shared__ float rinv[32];
    const int tid = threadIdx.x;
    const int bb  = blockIdx.x >> 7;
    const int l0  = (blockIdx.x & 127) << 5;

    const size_t xbase = (size_t)bb * CCH * LEN + l0;
    {
        const int i_hi = tid >> 3;
        const int l4   = (tid & 7) << 2;
        #pragma unroll
        for (int it = 0; it < 16; ++it) {
            const int i = it * 32 + i_hi;
            const float4 v = *(const float4*)&x[xbase + (size_t)i * LEN + l4];
            xt[i][l4 + 0] = f2bf(v.x);
            xt[i][l4 + 1] = f2bf(v.y);
            xt[i][l4 + 2] = f2bf(v.z);
            xt[i][l4 + 3] = f2bf(v.w);
        }
    }
    __syncthreads();
    {
        const int l = tid & 31, seg = tid >> 5;
        const int ibeg = seg * 64;
        float ss = 0.f;
        #pragma unroll 8
        for (int i = ibeg; i < ibeg + 64; ++i) {
            const float v = bf2f(xt[i][l]);
            ss += v * v;
        }
        red[seg][l] = ss;
    }
    __syncthreads();
    if (tid < 32) {
        float tot = 0.f;
        #pragma unroll
        for (int k2 = 0; k2 < 8; ++k2) tot += red[k2][tid];
        rinv[tid] = rsqrtf(tot * (1.f / 512.f) + 1e-6f);
    }
    __syncthreads();
    {
        const int l  = tid >> 3;
        const int i0 = (tid & 7) << 6;
        const float ri = rinv[l];
        const size_t ob = ((size_t)bb * LPAD + l0 + l + 1) * CCH + i0;
        for (int ii = 0; ii < 64; ii += 8) {
            u16x8 ov;
            #pragma unroll
            for (int jj = 0; jj < 8; ++jj) {
                const int i = i0 + ii + jj;
                float v = bf2f(xt[i][l]) * ri * g[i];
                ov[jj] = f2bf(silu_f(v));
            }
            *(u16x8*)&h_t[ob + ii] = ov;
        }
    }
}

// ---------------------------------------------------------------------------
// Conv-as-GEMM, m97 structure: global_load_lds x16B staging, single LDS buf,
// 2 barriers / K-step.  M=512(o) x N=65536(b,l) x K=3*512.
// 128x128 tile, 4 waves 2x2, per-wave 4x4 16x16x32 fragments, BK=64.
// Bsrc is the padded activation buffer [16][4098][512] (pad rows zeroed).
// EPI=1: h1 = silu(s*acc+bias) -> bf16 padded [b][l+1][o], via LDS transpose.
// EPI=2: out = s*acc + bias + resid -> fp32 [b][o][l].
template<int EPI>
__global__ __launch_bounds__(256)
void conv_gemm(const u16* __restrict__ Bsrc, const u16* __restrict__ Wq,
               const float* __restrict__ sptr, const float* __restrict__ bias,
               const float* __restrict__ resid, u16* __restrict__ outb,
               float* __restrict__ outf) {
    __shared__ u16 sbuf[2 * 128 * 64];          // 32 KB: A tile | B tile
    u16* lA = sbuf;
    u16* lB = sbuf + 8192;

    const int tid  = threadIdx.x;
    const int lane = tid & 63;
    const int wave = tid >> 6;
    const int wr = wave >> 1, wc = wave & 1;

    // XCD-aware chunking: 2048 blocks = 8 XCDs x 256; the 4 mt-blocks that
    // share a B-panel land on the same XCD.
    const int wgid = (blockIdx.x & 7) * 256 + (blockIdx.x >> 3);
    const int mt = wgid & 3;
    const int nt = wgid >> 2;
    const int o0 = mt << 7;
    const int bb = nt >> 5;
    const int l0 = (nt & 31) << 7;

    const int srow   = tid >> 3;        // 0..31
    const int schunk = (tid & 7) << 3;  // 0..56 u16

    const u16* wb = Wq + (size_t)(o0 + srow) * CCH + schunk;
    const u16* hb = Bsrc + ((size_t)bb * LPAD + l0 + srow) * CCH + schunk;
    u16* const dA = &sbuf[tid << 3];
    u16* const dB = &sbuf[8192 + (tid << 3)];

    const f32x4 zero4 = {0.f, 0.f, 0.f, 0.f};
    f32x4 acc[4][4];
    #pragma unroll
    for (int m = 0; m < 4; ++m)
        #pragma unroll
        for (int n = 0; n < 4; ++n)
            acc[m][n] = zero4;

    const int rba = (wr * 64 + (lane & 15)) * 64 + ((lane >> 4) << 3);
    const int rbb = (wc * 64 + (lane & 15)) * 64 + ((lane >> 4) << 3);

    for (int s = 0; s < 24; ++s) {
        const int ks = s >> 3;
        const int i0 = (s & 7) << 6;
        __syncthreads();                 // previous step's ds_reads done
        #pragma unroll
        for (int it = 0; it < 4; ++it) {
            async16(wb + ks * (CCH * CCH) + i0 + it * (32 * CCH), dA + it * 2048);
            async16(hb + (size_t)(it * 32 + ks) * CCH + i0, dB + it * 2048);
        }
        __syncthreads();                 // compiler drains vmcnt(0) before barrier
        #pragma unroll
        for (int kk = 0; kk < 2; ++kk) {
            bf16x8 av[4], bv[4];
            #pragma unroll
            for (int m = 0; m < 4; ++m)
                av[m] = *(const bf16x8*)&lA[rba + m * 1024 + kk * 32];
            #pragma unroll
            for (int n = 0; n < 4; ++n)
                bv[n] = *(const bf16x8*)&lB[rbb + n * 1024 + kk * 32];
            #pragma unroll
            for (int m = 0; m < 4; ++m)
                #pragma unroll
                for (int n = 0; n < 4; ++n)
                    acc[m][n] = __builtin_amdgcn_mfma_f32_16x16x32_bf16(
                        av[m], bv[n], acc[m][n], 0, 0, 0);
        }
    }

    const float sc = sptr[0];

    if (EPI == 1) {
        // transpose C tile through LDS (XOR-swizzled), then 16B coalesced stores
        __syncthreads();
        #pragma unroll
        for (int m = 0; m < 4; ++m) {
            const int o_loc = wr * 64 + m * 16 + ((lane >> 4) << 2);
            const int ob = o0 + o_loc;
            const float b0 = bias[ob + 0], b1 = bias[ob + 1];
            const float b2 = bias[ob + 2], b3 = bias[ob + 3];
            #pragma unroll
            for (int n = 0; n < 4; ++n) {
                const int l_loc = wc * 64 + n * 16 + (lane & 15);
                const f32x4 a = acc[m][n];
                u16x4 ov;
                ov[0] = f2bf(silu_f(sc * a[0] + b0));
                ov[1] = f2bf(silu_f(sc * a[1] + b1));
                ov[2] = f2bf(silu_f(sc * a[2] + b2));
                ov[3] = f2bf(silu_f(sc * a[3] + b3));
                char* p = (char*)sbuf + l_loc * 256 +
                          (((unsigned)(o_loc << 1)) ^ ((l_loc & 7) << 4));
                *(u16x4*)p = ov;
            }
        }
        __syncthreads();
        const int l_r = tid >> 1;                 // 0..127
        const int ho = (tid & 1) << 6;            // 0 or 64 (o offset)
        u16* gdst = outb + ((size_t)bb * LPAD + l0 + l_r + 1) * CCH + o0 + ho;
        char* srp = (char*)sbuf + l_r * 256;
        const int swz = (l_r & 7) << 4;
        #pragma unroll
        for (int c = 0; c < 8; ++c) {
            const uint4 v = *(const uint4*)(srp + (((ho << 1) + c * 16) ^ swz));
            *(uint4*)(gdst + c * 8) = v;
        }
    } else {
        const int lbase = l0 + wc * 64 + (lane & 15);
        const int obase = o0 + wr * 64 + ((lane >> 4) << 2);
        #pragma unroll
        for (int m = 0; m < 4; ++m) {
            const int ob = obase + m * 16;
            #pragma unroll
            for (int n = 0; n < 4; ++n) {
                const int l = lbase + n * 16;
                const f32x4 a = acc[m][n];
                #pragma unroll
                for (int j = 0; j < 4; ++j) {
                    const size_t idx = ((size_t)bb * CCH + (ob + j)) * LEN + l;
                    outf[idx] = sc * a[j] + bias[ob + j] + resid[idx];
                }
            }
        }
    }
}

// ---------------------------------------------------------------------------
extern "C" void kernel_launch(void* const* d_in, const int* in_sizes, int n_in,
                              void* d_out, int out_size, void* d_ws, size_t ws_size,
                              hipStream_t stream) {
    const float* x  = (const float*)d_in[0];
    const float* w1 = (const float*)d_in[1];
    const float* b1 = (const float*)d_in[2];
    const float* w2 = (const float*)d_in[3];
    const float* b2 = (const float*)d_in[4];
    const float* g  = (const float*)d_in[5];
    float* out = (float*)d_out;

    char* ws = (char*)d_ws;
    float* sv   = (float*)ws;
    float* part = (float*)(ws + 256);
    u16* wq1   = (u16*)(ws + 4096);
    u16* wq2   = (u16*)(ws + 4096 + 1572864);
    u16* h_t   = (u16*)(ws + 4096 + 2 * 1572864);                 // [16][4098][512] bf16
    u16* h1_t  = (u16*)(ws + 4096 + 2 * 1572864 + 67141632);      // [16][4098][512] bf16

    absmean_partial<<<dim3(256), dim3(256), 0, stream>>>(w1, w2, part);
    finalize_scale<<<dim3(1), dim3(256), 0, stream>>>(part, sv);
    quantize_w<<<dim3(3072), dim3(256), 0, stream>>>(w1, sv, 0, wq1);
    quantize_w<<<dim3(3072), dim3(256), 0, stream>>>(w2, sv, 1, wq2);
    zero_pads<<<dim3(64), dim3(256), 0, stream>>>(h_t, h1_t);
    rms_silu_transpose<<<dim3(2048), dim3(256), 0, stream>>>(x, g, h_t);
    conv_gemm<1><<<dim3(2048), dim3(256), 0, stream>>>(h_t, wq1, sv, b1, nullptr,
                                                       h1_t, nullptr);
    conv_gemm<2><<<dim3(2048), dim3(256), 0, stream>>>(h1_t, wq2, sv + 1, b2, x,
                                                       nullptr, out);
}

// Round 4
// 322.106 us; speedup vs baseline: 2.6778x; 1.3686x over previous
//
#include <hip/hip_runtime.h>

#define BATCH 16
#define CCH 512
#define LEN 4096
#define LPAD 4098

typedef unsigned short u16;
typedef __bf16 bf16x8 __attribute__((ext_vector_type(8)));
typedef float f32x4 __attribute__((ext_vector_type(4)));
typedef u16 u16x8 __attribute__((ext_vector_type(8)));
typedef u16 u16x4 __attribute__((ext_vector_type(4)));

__device__ __forceinline__ u16 f2bf(float f) {
    unsigned u = __float_as_uint(f);
    u = (u + 0x7fffu + ((u >> 16) & 1u)) >> 16;
    return (u16)u;
}
__device__ __forceinline__ float bf2f(u16 v) {
    return __uint_as_float(((unsigned)v) << 16);
}
__device__ __forceinline__ float silu_f(float v) {
    return v / (1.f + __expf(-v));
}
__device__ __forceinline__ void async16(const u16* g, u16* l) {
    __builtin_amdgcn_global_load_lds(
        (const __attribute__((address_space(1))) unsigned int*)g,
        (__attribute__((address_space(3))) unsigned int*)l, 16, 0, 0);
}

#define SBAR() __builtin_amdgcn_sched_barrier(0)
#define HWBAR() { SBAR(); __builtin_amdgcn_s_barrier(); SBAR(); }
#define WAIT_LGKM0() { asm volatile("s_waitcnt lgkmcnt(0)" ::: "memory"); SBAR(); }
#define WAIT_VM(n) { asm volatile("s_waitcnt vmcnt(" #n ")" ::: "memory"); SBAR(); }

// ---------------------------------------------------------------------------
__global__ __launch_bounds__(256)
void absmean_partial(const float* __restrict__ w1, const float* __restrict__ w2,
                     float* __restrict__ part) {
    const int tid = threadIdx.x;
    const int base = blockIdx.x * 3072;
    float s1 = 0.f, s2 = 0.f;
    for (int i = tid; i < 3072; i += 256) {
        s1 += fabsf(w1[base + i]);
        s2 += fabsf(w2[base + i]);
    }
    __shared__ float r1[256], r2[256];
    r1[tid] = s1; r2[tid] = s2;
    __syncthreads();
    for (int off = 128; off > 0; off >>= 1) {
        if (tid < off) { r1[tid] += r1[tid + off]; r2[tid] += r2[tid + off]; }
        __syncthreads();
    }
    if (tid == 0) { part[blockIdx.x] = r1[0]; part[256 + blockIdx.x] = r2[0]; }
}

__global__ __launch_bounds__(256)
void finalize_scale(const float* __restrict__ part, float* __restrict__ sv) {
    const int tid = threadIdx.x;
    __shared__ float r1[256], r2[256];
    r1[tid] = part[tid]; r2[tid] = part[256 + tid];
    __syncthreads();
    for (int off = 128; off > 0; off >>= 1) {
        if (tid < off) { r1[tid] += r1[tid + off]; r2[tid] += r2[tid + off]; }
        __syncthreads();
    }
    if (tid == 0) {
        sv[0] = fmaxf(r1[0] * (1.f / 786432.f), 1e-5f);
        sv[1] = fmaxf(r2[0] * (1.f / 786432.f), 1e-5f);
    }
}

// ---------------------------------------------------------------------------
__global__ __launch_bounds__(256)
void quantize_w(const float* __restrict__ w, const float* __restrict__ sv,
                int sidx, u16* __restrict__ wqt) {
    const int idx = blockIdx.x * 256 + threadIdx.x;
    const float s = sv[sidx];
    float q = rintf(w[idx] / s);
    q = fmaxf(-1.f, fminf(1.f, q));
    const int o   = idx / 1536;
    const int rem = idx - o * 1536;
    const int i   = rem / 3;
    const int k   = rem - i * 3;
    wqt[k * (CCH * CCH) + o * CCH + i] = f2bf(q);
}

__global__ __launch_bounds__(256)
void zero_pads(u16* __restrict__ h, u16* __restrict__ h1) {
    const int idx = blockIdx.x * 256 + threadIdx.x;   // [0, 16384)
    const int b = idx >> 10;
    const int r = (idx >> 9) & 1;
    const int i = idx & 511;
    const size_t off = ((size_t)b * LPAD + (r ? (LPAD - 1) : 0)) * CCH + i;
    h[off] = 0;
    h1[off] = 0;
}

// ---------------------------------------------------------------------------
__global__ __launch_bounds__(256)
void rms_silu_transpose(const float* __restrict__ x, const float* __restrict__ g,
                        u16* __restrict__ h_t) {
    __shared__ u16   xt[CCH][33];
    __shared__ float red[8][32];
    __shared__ float rinv[32];
    const int tid = threadIdx.x;
    const int bb  = blockIdx.x >> 7;
    const int l0  = (blockIdx.x & 127) << 5;

    const size_t xbase = (size_t)bb * CCH * LEN + l0;
    {
        const int i_hi = tid >> 3;
        const int l4   = (tid & 7) << 2;
        #pragma unroll
        for (int it = 0; it < 16; ++it) {
            const int i = it * 32 + i_hi;
            const float4 v = *(const float4*)&x[xbase + (size_t)i * LEN + l4];
            xt[i][l4 + 0] = f2bf(v.x);
            xt[i][l4 + 1] = f2bf(v.y);
            xt[i][l4 + 2] = f2bf(v.z);
            xt[i][l4 + 3] = f2bf(v.w);
        }
    }
    __syncthreads();
    {
        const int l = tid & 31, seg = tid >> 5;
        const int ibeg = seg * 64;
        float ss = 0.f;
        #pragma unroll 8
        for (int i = ibeg; i < ibeg + 64; ++i) {
            const float v = bf2f(xt[i][l]);
            ss += v * v;
        }
        red[seg][l] = ss;
    }
    __syncthreads();
    if (tid < 32) {
        float tot = 0.f;
        #pragma unroll
        for (int k2 = 0; k2 < 8; ++k2) tot += red[k2][tid];
        rinv[tid] = rsqrtf(tot * (1.f / 512.f) + 1e-6f);
    }
    __syncthreads();
    {
        const int l  = tid >> 3;
        const int i0 = (tid & 7) << 6;
        const float ri = rinv[l];
        const size_t ob = ((size_t)bb * LPAD + l0 + l + 1) * CCH + i0;
        for (int ii = 0; ii < 64; ii += 8) {
            u16x8 ov;
            #pragma unroll
            for (int jj = 0; jj < 8; ++jj) {
                const int i = i0 + ii + jj;
                float v = bf2f(xt[i][l]) * ri * g[i];
                ov[jj] = f2bf(silu_f(v));
            }
            *(u16x8*)&h_t[ob + ii] = ov;
        }
    }
}

// ---------------------------------------------------------------------------
// Conv-as-GEMM, 8-phase 256x256 template (T1+T2+T3+T4+T5).
// M=512(o) x N=65536(b,l) x K=24 steps of 64.  512 threads = 8 waves (2M x 4N),
// per-wave 128x64 output (8x4 16x16x32 frags).  LDS 128 KiB: buf0=even K-tile,
// buf1=odd K-tile; each buf = A(256x64) + B(256x64) bf16, XOR-swizzled rows.
// Counted vmcnt(4) at phases 4/8; raw s_barrier (no vmcnt(0) drain).
template<int EPI>
__global__ __launch_bounds__(512)
void conv_gemm8(const u16* __restrict__ Bsrc, const u16* __restrict__ Wq,
                const float* __restrict__ sptr, const float* __restrict__ bias,
                const float* __restrict__ resid, u16* __restrict__ outb,
                float* __restrict__ outf) {
    extern __shared__ u16 lds[];          // 65536 u16 = 128 KiB
    const int tid  = threadIdx.x;
    const int lane = tid & 63;
    const int wave = tid >> 6;
    const int wm = wave >> 2;             // 0..1  (M half)
    const int wn = wave & 3;              // 0..3  (N quarter)

    // T1: bijective XCD chunking (512 = 8 x 64); mt-pairs share a B-panel.
    const int wgid = (blockIdx.x & 7) * 64 + (blockIdx.x >> 3);
    const int mt = wgid & 1;
    const int nt = wgid >> 1;
    const int o0 = mt << 8;
    const int bb = nt >> 4;
    const int l0 = (nt & 15) << 8;

    // staging geometry: thread -> linear LDS (r = j*64 + tid/8, c = (tid&7)*8 u16)
    const int sr  = tid >> 3;                              // 0..63
    const int scu = ((tid & 7) << 3) ^ ((sr & 7) << 3);    // pre-swizzled src col
    const int sdst = tid << 3;                             // u16 within 4096-u16 chunk

    const u16* aSrcBase = Wq + (size_t)o0 * CCH + scu;
    const u16* bSrcBase = Bsrc + ((size_t)bb * LPAD + l0) * CCH + scu;

    // stage one half-tile: T=0 A, T=1 B; dest buf `pb`; K-tile params ks2/i02
    auto stage = [&](int pb, int T, int h, int ks2, int i02) {
        #pragma unroll
        for (int j = 0; j < 2; ++j) {
            const int r = h * 128 + j * 64 + sr;
            const u16* src = (T == 0)
                ? aSrcBase + ks2 * (CCH * CCH) + r * CCH + i02
                : bSrcBase + (size_t)(r + ks2) * CCH + i02;
            async16(src, &lds[pb * 32768 + T * 16384 + h * 8192 + j * 4096 + sdst]);
        }
    };

    // ds_read geometry (swizzled).  kk=0 cols 0..31, kk=1 cols 32..63.
    const int swz = (lane & 7) << 3;
    const int c0 = ((lane >> 4) << 3) ^ swz;
    const int c1 = (((lane >> 4) << 3) + 32) ^ swz;   // FIXED: +32, not +16
    const int aB = wm * 8192 + (lane & 15) * 64;
    const int bB = 16384 + (wn >> 1) * 8192 + ((wn & 1) * 64 + (lane & 15)) * 64;

    bf16x8 ar[4][2], br[4][2];
    f32x4 acc[8][4];
    #pragma unroll
    for (int m = 0; m < 8; ++m)
        #pragma unroll
        for (int n = 0; n < 4; ++n)
            acc[m][n] = (f32x4){0.f, 0.f, 0.f, 0.f};

    auto rdA = [&](int cbuf, int mh) {
        #pragma unroll
        for (int mm = 0; mm < 4; ++mm) {
            const int base = cbuf * 32768 + aB + (mh * 4 + mm) * 1024;
            ar[mm][0] = *(const bf16x8*)&lds[base + c0];
            ar[mm][1] = *(const bf16x8*)&lds[base + c1];
        }
    };
    auto rdB = [&](int cbuf, int nh) {
        #pragma unroll
        for (int nn = 0; nn < 2; ++nn) {
            const int fn = nh * 2 + nn;
            const int base = cbuf * 32768 + bB + fn * 1024;
            br[fn][0] = *(const bf16x8*)&lds[base + c0];
            br[fn][1] = *(const bf16x8*)&lds[base + c1];
        }
    };
    auto mfma16 = [&](int mh, int nh) {
        __builtin_amdgcn_s_setprio(1);
        #pragma unroll
        for (int kk = 0; kk < 2; ++kk)
            #pragma unroll
            for (int mm = 0; mm < 4; ++mm)
                #pragma unroll
                for (int nn = 0; nn < 2; ++nn)
                    acc[mh * 4 + mm][nh * 2 + nn] =
                        __builtin_amdgcn_mfma_f32_16x16x32_bf16(
                            ar[mm][kk], br[nh * 2 + nn][kk],
                            acc[mh * 4 + mm][nh * 2 + nn], 0, 0, 0);
        __builtin_amdgcn_s_setprio(0);
    };

    // prologue: tile0 (A+B) into buf0, tile1-B into buf1  (tile1-A comes in ph1/2)
    stage(0, 0, 0, 0, 0);
    stage(0, 0, 1, 0, 0);
    stage(0, 1, 0, 0, 0);
    stage(0, 1, 1, 0, 0);
    stage(1, 1, 0, 0, 64);
    stage(1, 1, 1, 0, 64);
    WAIT_VM(4);
    HWBAR();

    auto iterbody = [&](int j, bool full) {
        const int tO  = 2 * j + 1;           // odd tile computed this iter
        const int tE2 = 2 * j + 2;           // next even tile (staged into buf0)
        const int tO2 = 2 * j + 3;           // next odd tile (B staged into buf1)
        const int ksO = tO >> 3,  iO  = (tO & 7) << 6;
        const int ksE = tE2 >> 3, iE  = (tE2 & 7) << 6;
        const int ksP = tO2 >> 3, iP  = (tO2 & 7) << 6;
        // ph1: even-tile Q(0,0); stage odd-tile A-h0
        rdA(0, 0); rdB(0, 0);
        stage(1, 0, 0, ksO, iO);
        HWBAR(); WAIT_LGKM0(); mfma16(0, 0); HWBAR();
        // ph2: Q(0,1); stage odd-tile A-h1
        rdB(0, 1);
        stage(1, 0, 1, ksO, iO);
        HWBAR(); WAIT_LGKM0(); mfma16(0, 1); HWBAR();
        // ph3: Q(1,1); stage next-even B-h0
        rdA(0, 1);
        if (full) stage(0, 1, 0, ksE, iE);
        HWBAR(); WAIT_LGKM0(); mfma16(1, 1); HWBAR();
        // ph4: Q(1,0); stage next-even B-h1; counted vmcnt
        if (full) stage(0, 1, 1, ksE, iE);
        HWBAR(); mfma16(1, 0);
        if (full) { WAIT_VM(4); } else { WAIT_VM(0); }
        HWBAR();
        // ph5: odd-tile Q(0,0); stage next-even A-h0
        rdA(1, 0); rdB(1, 0);
        if (full) stage(0, 0, 0, ksE, iE);
        HWBAR(); WAIT_LGKM0(); mfma16(0, 0); HWBAR();
        // ph6: Q(0,1); stage next-even A-h1
        rdB(1, 1);
        if (full) stage(0, 0, 1, ksE, iE);
        HWBAR(); WAIT_LGKM0(); mfma16(0, 1); HWBAR();
        // ph7: Q(1,1); stage next-odd B-h0
        rdA(1, 1);
        if (full) stage(1, 1, 0, ksP, iP);
        HWBAR(); WAIT_LGKM0(); mfma16(1, 1); HWBAR();
        // ph8: Q(1,0); stage next-odd B-h1; counted vmcnt
        if (full) stage(1, 1, 1, ksP, iP);
        HWBAR(); mfma16(1, 0);
        if (full) { WAIT_VM(4); }
        HWBAR();
    };

    for (int j = 0; j < 11; ++j) iterbody(j, true);
    iterbody(11, false);

    // epilogue
    const float sc = sptr[0];

    if (EPI == 1) {
        // silu(sc*acc+bias) -> LDS [l_loc][o_loc] bf16 (XOR swizzled 16B chunks),
        // then coalesced stores: 4 consecutive lanes fill one 64B sector.
        #pragma unroll
        for (int m = 0; m < 8; ++m) {
            const int o_loc = wm * 128 + m * 16 + ((lane >> 4) << 2);
            const int ob = o0 + o_loc;
            const float b0 = bias[ob + 0], b1 = bias[ob + 1];
            const float b2 = bias[ob + 2], b3 = bias[ob + 3];
            #pragma unroll
            for (int n = 0; n < 4; ++n) {
                const int l_loc = wn * 64 + n * 16 + (lane & 15);
                const f32x4 a = acc[m][n];
                u16x4 ov;
                ov[0] = f2bf(silu_f(sc * a[0] + b0));
                ov[1] = f2bf(silu_f(sc * a[1] + b1));
                ov[2] = f2bf(silu_f(sc * a[2] + b2));
                ov[3] = f2bf(silu_f(sc * a[3] + b3));
                char* p = (char*)lds + l_loc * 512 +
                          (((unsigned)(o_loc << 1)) ^ ((l_loc & 7) << 4));
                *(u16x4*)p = ov;
            }
        }
        __syncthreads();
        const int l_r = tid >> 2;            // 0..127
        const int oq  = (tid & 3) << 3;      // u16: 0,8,16,24
        #pragma unroll
        for (int pass = 0; pass < 2; ++pass) {
            const int lr = l_r + pass * 128;
            u16* gdst = outb + ((size_t)bb * LPAD + l0 + lr + 1) * CCH + o0 + oq;
            char* srp = (char*)lds + lr * 512;
            const int swz2 = (lr & 7) << 4;
            #pragma unroll
            for (int c = 0; c < 8; ++c) {
                const uint4 v = *(const uint4*)(srp + (((oq << 1) + c * 64) ^ swz2));
                *(uint4*)(gdst + c * 32) = v;
            }
        }
    } else {
        const int lbase = l0 + wn * 64 + (lane & 15);
        const int obase = o0 + wm * 128 + ((lane >> 4) << 2);
        #pragma unroll
        for (int m = 0; m < 8; ++m) {
            const int ob = obase + m * 16;
            #pragma unroll
            for (int n = 0; n < 4; ++n) {
                const int l = lbase + n * 16;
                const f32x4 a = acc[m][n];
                #pragma unroll
                for (int jj = 0; jj < 4; ++jj) {
                    const size_t idx = ((size_t)bb * CCH + (ob + jj)) * LEN + l;
                    outf[idx] = sc * a[jj] + bias[ob + jj] + resid[idx];
                }
            }
        }
    }
}

// ---------------------------------------------------------------------------
extern "C" void kernel_launch(void* const* d_in, const int* in_sizes, int n_in,
                              void* d_out, int out_size, void* d_ws, size_t ws_size,
                              hipStream_t stream) {
    const float* x  = (const float*)d_in[0];
    const float* w1 = (const float*)d_in[1];
    const float* b1 = (const float*)d_in[2];
    const float* w2 = (const float*)d_in[3];
    const float* b2 = (const float*)d_in[4];
    const float* g  = (const float*)d_in[5];
    float* out = (float*)d_out;

    char* ws = (char*)d_ws;
    float* sv   = (float*)ws;
    float* part = (float*)(ws + 256);
    u16* wq1   = (u16*)(ws + 4096);
    u16* wq2   = (u16*)(ws + 4096 + 1572864);
    u16* h_t   = (u16*)(ws + 4096 + 2 * 1572864);                 // [16][4098][512] bf16
    u16* h1_t  = (u16*)(ws + 4096 + 2 * 1572864 + 67141632);      // [16][4098][512] bf16

    hipFuncSetAttribute((const void*)conv_gemm8<1>,
                        hipFuncAttributeMaxDynamicSharedMemorySize, 131072);
    hipFuncSetAttribute((const void*)conv_gemm8<2>,
                        hipFuncAttributeMaxDynamicSharedMemorySize, 131072);

    absmean_partial<<<dim3(256), dim3(256), 0, stream>>>(w1, w2, part);
    finalize_scale<<<dim3(1), dim3(256), 0, stream>>>(part, sv);
    quantize_w<<<dim3(3072), dim3(256), 0, stream>>>(w1, sv, 0, wq1);
    quantize_w<<<dim3(3072), dim3(256), 0, stream>>>(w2, sv, 1, wq2);
    zero_pads<<<dim3(64), dim3(256), 0, stream>>>(h_t, h1_t);
    rms_silu_transpose<<<dim3(2048), dim3(256), 0, stream>>>(x, g, h_t);
    conv_gemm8<1><<<dim3(512), dim3(512), 131072, stream>>>(h_t, wq1, sv, b1,
                                                            nullptr, h1_t, nullptr);
    conv_gemm8<2><<<dim3(512), dim3(512), 131072, stream>>>(h1_t, wq2, sv + 1, b2,
                                                            x, nullptr, out);
}

// Round 5
// 314.545 us; speedup vs baseline: 2.7422x; 1.0240x over previous
//
#include <hip/hip_runtime.h>

#define BATCH 16
#define CCH 512
#define LEN 4096
#define LPAD 4098

typedef unsigned short u16;
typedef __bf16 bf16x8 __attribute__((ext_vector_type(8)));
typedef float f32x4 __attribute__((ext_vector_type(4)));
typedef u16 u16x8 __attribute__((ext_vector_type(8)));
typedef u16 u16x4 __attribute__((ext_vector_type(4)));

__device__ __forceinline__ u16 f2bf(float f) {
    unsigned u = __float_as_uint(f);
    u = (u + 0x7fffu + ((u >> 16) & 1u)) >> 16;
    return (u16)u;
}
__device__ __forceinline__ float bf2f(u16 v) {
    return __uint_as_float(((unsigned)v) << 16);
}
__device__ __forceinline__ float silu_f(float v) {
    return v / (1.f + __expf(-v));
}
__device__ __forceinline__ void async16(const u16* g, u16* l) {
    __builtin_amdgcn_global_load_lds(
        (const __attribute__((address_space(1))) unsigned int*)g,
        (__attribute__((address_space(3))) unsigned int*)l, 16, 0, 0);
}

#define SBAR() __builtin_amdgcn_sched_barrier(0)
#define HWBAR() { SBAR(); __builtin_amdgcn_s_barrier(); SBAR(); }
#define WAIT_LGKM0() { asm volatile("s_waitcnt lgkmcnt(0)" ::: "memory"); SBAR(); }
#define WAIT_VM(n) { asm volatile("s_waitcnt vmcnt(" #n ")" ::: "memory"); SBAR(); }

// ---------------------------------------------------------------------------
__global__ __launch_bounds__(256)
void absmean_partial(const float* __restrict__ w1, const float* __restrict__ w2,
                     float* __restrict__ part) {
    const int tid = threadIdx.x;
    const int base = blockIdx.x * 3072;
    float s1 = 0.f, s2 = 0.f;
    for (int i = tid; i < 3072; i += 256) {
        s1 += fabsf(w1[base + i]);
        s2 += fabsf(w2[base + i]);
    }
    __shared__ float r1[256], r2[256];
    r1[tid] = s1; r2[tid] = s2;
    __syncthreads();
    for (int off = 128; off > 0; off >>= 1) {
        if (tid < off) { r1[tid] += r1[tid + off]; r2[tid] += r2[tid + off]; }
        __syncthreads();
    }
    if (tid == 0) { part[blockIdx.x] = r1[0]; part[256 + blockIdx.x] = r2[0]; }
}

__global__ __launch_bounds__(256)
void finalize_scale(const float* __restrict__ part, float* __restrict__ sv) {
    const int tid = threadIdx.x;
    __shared__ float r1[256], r2[256];
    r1[tid] = part[tid]; r2[tid] = part[256 + tid];
    __syncthreads();
    for (int off = 128; off > 0; off >>= 1) {
        if (tid < off) { r1[tid] += r1[tid + off]; r2[tid] += r2[tid + off]; }
        __syncthreads();
    }
    if (tid == 0) {
        sv[0] = fmaxf(r1[0] * (1.f / 786432.f), 1e-5f);
        sv[1] = fmaxf(r2[0] * (1.f / 786432.f), 1e-5f);
    }
}

// ---------------------------------------------------------------------------
__global__ __launch_bounds__(256)
void quantize_w(const float* __restrict__ w, const float* __restrict__ sv,
                int sidx, u16* __restrict__ wqt) {
    const int idx = blockIdx.x * 256 + threadIdx.x;
    const float s = sv[sidx];
    float q = rintf(w[idx] / s);
    q = fmaxf(-1.f, fminf(1.f, q));
    const int o   = idx / 1536;
    const int rem = idx - o * 1536;
    const int i   = rem / 3;
    const int k   = rem - i * 3;
    wqt[k * (CCH * CCH) + o * CCH + i] = f2bf(q);
}

__global__ __launch_bounds__(256)
void zero_pads(u16* __restrict__ h, u16* __restrict__ h1) {
    const int idx = blockIdx.x * 256 + threadIdx.x;   // [0, 16384)
    const int b = idx >> 10;
    const int r = (idx >> 9) & 1;
    const int i = idx & 511;
    const size_t off = ((size_t)b * LPAD + (r ? (LPAD - 1) : 0)) * CCH + i;
    h[off] = 0;
    h1[off] = 0;
}

// ---------------------------------------------------------------------------
__global__ __launch_bounds__(256)
void rms_silu_transpose(const float* __restrict__ x, const float* __restrict__ g,
                        u16* __restrict__ h_t) {
    __shared__ u16   xt[CCH][33];
    __shared__ float red[8][32];
    __shared__ float rinv[32];
    const int tid = threadIdx.x;
    const int bb  = blockIdx.x >> 7;
    const int l0  = (blockIdx.x & 127) << 5;

    const size_t xbase = (size_t)bb * CCH * LEN + l0;
    {
        const int i_hi = tid >> 3;
        const int l4   = (tid & 7) << 2;
        #pragma unroll
        for (int it = 0; it < 16; ++it) {
            const int i = it * 32 + i_hi;
            const float4 v = *(const float4*)&x[xbase + (size_t)i * LEN + l4];
            xt[i][l4 + 0] = f2bf(v.x);
            xt[i][l4 + 1] = f2bf(v.y);
            xt[i][l4 + 2] = f2bf(v.z);
            xt[i][l4 + 3] = f2bf(v.w);
        }
    }
    __syncthreads();
    {
        const int l = tid & 31, seg = tid >> 5;
        const int ibeg = seg * 64;
        float ss = 0.f;
        #pragma unroll 8
        for (int i = ibeg; i < ibeg + 64; ++i) {
            const float v = bf2f(xt[i][l]);
            ss += v * v;
        }
        red[seg][l] = ss;
    }
    __syncthreads();
    if (tid < 32) {
        float tot = 0.f;
        #pragma unroll
        for (int k2 = 0; k2 < 8; ++k2) tot += red[k2][tid];
        rinv[tid] = rsqrtf(tot * (1.f / 512.f) + 1e-6f);
    }
    __syncthreads();
    {
        const int l  = tid >> 3;
        const int i0 = (tid & 7) << 6;
        const float ri = rinv[l];
        const size_t ob = ((size_t)bb * LPAD + l0 + l + 1) * CCH + i0;
        for (int ii = 0; ii < 64; ii += 8) {
            u16x8 ov;
            #pragma unroll
            for (int jj = 0; jj < 8; ++jj) {
                const int i = i0 + ii + jj;
                float v = bf2f(xt[i][l]) * ri * g[i];
                ov[jj] = f2bf(silu_f(v));
            }
            *(u16x8*)&h_t[ob + ii] = ov;
        }
    }
}

// ---------------------------------------------------------------------------
// Conv-as-GEMM, 256x256 tile, 64-MFMA-per-barrier K-loop (AITER granularity).
// Per K-tile (BK=64): stage full next tile -> other buffer (8 gload_lds),
// 24 ds_read_b128 + 64 MFMA compiler-interleaved, lgkm0 + vm0 + one barrier.
// K-tile order is ks-inner: t -> (ks = t%3, i0 = (t/3)*64) for 3x B L2 reuse.
// T1 XCD chunking, T2 XOR swizzle, T5 setprio retained.
template<int EPI>
__global__ __launch_bounds__(512)
void conv_gemm8(const u16* __restrict__ Bsrc, const u16* __restrict__ Wq,
                const float* __restrict__ sptr, const float* __restrict__ bias,
                const float* __restrict__ resid, u16* __restrict__ outb,
                float* __restrict__ outf) {
    extern __shared__ u16 lds[];          // 65536 u16 = 128 KiB
    const int tid  = threadIdx.x;
    const int lane = tid & 63;
    const int wave = tid >> 6;
    const int wm = wave >> 2;             // 0..1  (M half)
    const int wn = wave & 3;              // 0..3  (N quarter)

    // T1: bijective XCD chunking (512 = 8 x 64); mt-pairs share a B-panel.
    const int wgid = (blockIdx.x & 7) * 64 + (blockIdx.x >> 3);
    const int mt = wgid & 1;
    const int nt = wgid >> 1;
    const int o0 = mt << 8;
    const int bb = nt >> 4;
    const int l0 = (nt & 15) << 8;

    // staging geometry: thread -> linear LDS (r = j*64 + tid/8, c = (tid&7)*8 u16)
    const int sr  = tid >> 3;                              // 0..63
    const int scu = ((tid & 7) << 3) ^ ((sr & 7) << 3);    // pre-swizzled src col
    const int sdst = tid << 3;                             // u16 within 4096-u16 chunk

    const u16* aSrcBase = Wq + (size_t)o0 * CCH + scu;
    const u16* bSrcBase = Bsrc + ((size_t)bb * LPAD + l0) * CCH + scu;

    // stage one half-tile: T=0 A, T=1 B; dest buf `pb`; K-tile params ks2/i02
    auto stage = [&](int pb, int T, int h, int ks2, int i02) {
        #pragma unroll
        for (int j = 0; j < 2; ++j) {
            const int r = h * 128 + j * 64 + sr;
            const u16* src = (T == 0)
                ? aSrcBase + ks2 * (CCH * CCH) + r * CCH + i02
                : bSrcBase + (size_t)(r + ks2) * CCH + i02;
            async16(src, &lds[pb * 32768 + T * 16384 + h * 8192 + j * 4096 + sdst]);
        }
    };
    auto stage_full = [&](int pb, int ks2, int i02) {
        stage(pb, 0, 0, ks2, i02);
        stage(pb, 0, 1, ks2, i02);
        stage(pb, 1, 0, ks2, i02);
        stage(pb, 1, 1, ks2, i02);
    };

    // ds_read geometry (swizzled).  kk=0 cols 0..31, kk=1 cols 32..63.
    const int swz = (lane & 7) << 3;
    const int c0 = ((lane >> 4) << 3) ^ swz;
    const int c1 = (((lane >> 4) << 3) + 32) ^ swz;
    const int aB = wm * 8192 + (lane & 15) * 64;
    const int bB = 16384 + (wn >> 1) * 8192 + ((wn & 1) * 64 + (lane & 15)) * 64;

    bf16x8 ar[4][2], br[4][2];
    f32x4 acc[8][4];
    #pragma unroll
    for (int m = 0; m < 8; ++m)
        #pragma unroll
        for (int n = 0; n < 4; ++n)
            acc[m][n] = (f32x4){0.f, 0.f, 0.f, 0.f};

    auto rdA = [&](int cbuf, int mh) {
        #pragma unroll
        for (int mm = 0; mm < 4; ++mm) {
            const int base = cbuf * 32768 + aB + (mh * 4 + mm) * 1024;
            ar[mm][0] = *(const bf16x8*)&lds[base + c0];
            ar[mm][1] = *(const bf16x8*)&lds[base + c1];
        }
    };
    auto rdB = [&](int cbuf, int nh) {
        #pragma unroll
        for (int nn = 0; nn < 2; ++nn) {
            const int fn = nh * 2 + nn;
            const int base = cbuf * 32768 + bB + fn * 1024;
            br[fn][0] = *(const bf16x8*)&lds[base + c0];
            br[fn][1] = *(const bf16x8*)&lds[base + c1];
        }
    };
    auto mfma16 = [&](int mh, int nh) {
        __builtin_amdgcn_s_setprio(1);
        #pragma unroll
        for (int kk = 0; kk < 2; ++kk)
            #pragma unroll
            for (int mm = 0; mm < 4; ++mm)
                #pragma unroll
                for (int nn = 0; nn < 2; ++nn)
                    acc[mh * 4 + mm][nh * 2 + nn] =
                        __builtin_amdgcn_mfma_f32_16x16x32_bf16(
                            ar[mm][kk], br[nh * 2 + nn][kk],
                            acc[mh * 4 + mm][nh * 2 + nn], 0, 0, 0);
        __builtin_amdgcn_s_setprio(0);
    };

    // prologue: tile 0 -> buf0, wait, barrier
    stage_full(0, 0, 0);
    WAIT_VM(0);
    HWBAR();

    // main loop: one barrier per K-tile, 64 MFMA between barriers
    for (int t = 0; t < 24; ++t) {
        const int cur = t & 1;
        if (t + 1 < 24) {
            const int tn = t + 1;
            stage_full(cur ^ 1, tn % 3, (tn / 3) << 6);   // prefetch next tile
        }
        rdB(cur, 0); rdB(cur, 1);      // all of B: 8 ds_read_b128
        rdA(cur, 0);                   // A half 0: 8 reads
        mfma16(0, 0); mfma16(0, 1);    // 32 MFMA
        rdA(cur, 1);                   // A half 1: 8 reads
        mfma16(1, 1); mfma16(1, 0);    // 32 MFMA
        WAIT_LGKM0();                  // all reads of buf[cur] retired (WAR safety)
        WAIT_VM(0);                    // next tile landed (issued a full tile ago)
        HWBAR();
    }

    // epilogue
    const float sc = sptr[0];

    if (EPI == 1) {
        // silu(sc*acc+bias) -> LDS [l_loc][o_loc] bf16 (XOR swizzled 16B chunks),
        // then coalesced stores: 4 consecutive lanes fill one 64B sector.
        #pragma unroll
        for (int m = 0; m < 8; ++m) {
            const int o_loc = wm * 128 + m * 16 + ((lane >> 4) << 2);
            const int ob = o0 + o_loc;
            const float b0 = bias[ob + 0], b1 = bias[ob + 1];
            const float b2 = bias[ob + 2], b3 = bias[ob + 3];
            #pragma unroll
            for (int n = 0; n < 4; ++n) {
                const int l_loc = wn * 64 + n * 16 + (lane & 15);
                const f32x4 a = acc[m][n];
                u16x4 ov;
                ov[0] = f2bf(silu_f(sc * a[0] + b0));
                ov[1] = f2bf(silu_f(sc * a[1] + b1));
                ov[2] = f2bf(silu_f(sc * a[2] + b2));
                ov[3] = f2bf(silu_f(sc * a[3] + b3));
                char* p = (char*)lds + l_loc * 512 +
                          (((unsigned)(o_loc << 1)) ^ ((l_loc & 7) << 4));
                *(u16x4*)p = ov;
            }
        }
        __syncthreads();
        const int l_r = tid >> 2;            // 0..127
        const int oq  = (tid & 3) << 3;      // u16: 0,8,16,24
        #pragma unroll
        for (int pass = 0; pass < 2; ++pass) {
            const int lr = l_r + pass * 128;
            u16* gdst = outb + ((size_t)bb * LPAD + l0 + lr + 1) * CCH + o0 + oq;
            char* srp = (char*)lds + lr * 512;
            const int swz2 = (lr & 7) << 4;
            #pragma unroll
            for (int c = 0; c < 8; ++c) {
                const uint4 v = *(const uint4*)(srp + (((oq << 1) + c * 64) ^ swz2));
                *(uint4*)(gdst + c * 32) = v;
            }
        }
    } else {
        const int lbase = l0 + wn * 64 + (lane & 15);
        const int obase = o0 + wm * 128 + ((lane >> 4) << 2);
        #pragma unroll
        for (int m = 0; m < 8; ++m) {
            const int ob = obase + m * 16;
            #pragma unroll
            for (int n = 0; n < 4; ++n) {
                const int l = lbase + n * 16;
                const f32x4 a = acc[m][n];
                #pragma unroll
                for (int jj = 0; jj < 4; ++jj) {
                    const size_t idx = ((size_t)bb * CCH + (ob + jj)) * LEN + l;
                    outf[idx] = sc * a[jj] + bias[ob + jj] + resid[idx];
                }
            }
        }
    }
}

// ---------------------------------------------------------------------------
extern "C" void kernel_launch(void* const* d_in, const int* in_sizes, int n_in,
                              void* d_out, int out_size, void* d_ws, size_t ws_size,
                              hipStream_t stream) {
    const float* x  = (const float*)d_in[0];
    const float* w1 = (const float*)d_in[1];
    const float* b1 = (const float*)d_in[2];
    const float* w2 = (const float*)d_in[3];
    const float* b2 = (const float*)d_in[4];
    const float* g  = (const float*)d_in[5];
    float* out = (float*)d_out;

    char* ws = (char*)d_ws;
    float* sv   = (float*)ws;
    float* part = (float*)(ws + 256);
    u16* wq1   = (u16*)(ws + 4096);
    u16* wq2   = (u16*)(ws + 4096 + 1572864);
    u16* h_t   = (u16*)(ws + 4096 + 2 * 1572864);                 // [16][4098][512] bf16
    u16* h1_t  = (u16*)(ws + 4096 + 2 * 1572864 + 67141632);      // [16][4098][512] bf16

    hipFuncSetAttribute((const void*)conv_gemm8<1>,
                        hipFuncAttributeMaxDynamicSharedMemorySize, 131072);
    hipFuncSetAttribute((const void*)conv_gemm8<2>,
                        hipFuncAttributeMaxDynamicSharedMemorySize, 131072);

    absmean_partial<<<dim3(256), dim3(256), 0, stream>>>(w1, w2, part);
    finalize_scale<<<dim3(1), dim3(256), 0, stream>>>(part, sv);
    quantize_w<<<dim3(3072), dim3(256), 0, stream>>>(w1, sv, 0, wq1);
    quantize_w<<<dim3(3072), dim3(256), 0, stream>>>(w2, sv, 1, wq2);
    zero_pads<<<dim3(64), dim3(256), 0, stream>>>(h_t, h1_t);
    rms_silu_transpose<<<dim3(2048), dim3(256), 0, stream>>>(x, g, h_t);
    conv_gemm8<1><<<dim3(512), dim3(512), 131072, stream>>>(h_t, wq1, sv, b1,
                                                            nullptr, h1_t, nullptr);
    conv_gemm8<2><<<dim3(512), dim3(512), 131072, stream>>>(h1_t, wq2, sv + 1, b2,
                                                            x, nullptr, out);
}

// Round 6
// 306.914 us; speedup vs baseline: 2.8104x; 1.0249x over previous
//
#include <hip/hip_runtime.h>

#define BATCH 16
#define CCH 512
#define LEN 4096
#define LPAD 4098

typedef unsigned short u16;
typedef __bf16 bf16x8 __attribute__((ext_vector_type(8)));
typedef float f32x4 __attribute__((ext_vector_type(4)));
typedef u16 u16x8 __attribute__((ext_vector_type(8)));
typedef u16 u16x4 __attribute__((ext_vector_type(4)));

__device__ __forceinline__ u16 f2bf(float f) {
    unsigned u = __float_as_uint(f);
    u = (u + 0x7fffu + ((u >> 16) & 1u)) >> 16;
    return (u16)u;
}
__device__ __forceinline__ float bf2f(u16 v) {
    return __uint_as_float(((unsigned)v) << 16);
}
__device__ __forceinline__ float silu_f(float v) {
    return v / (1.f + __expf(-v));
}
__device__ __forceinline__ void async16(const u16* g, u16* l) {
    __builtin_amdgcn_global_load_lds(
        (const __attribute__((address_space(1))) unsigned int*)g,
        (__attribute__((address_space(3))) unsigned int*)l, 16, 0, 0);
}

#define SBAR() __builtin_amdgcn_sched_barrier(0)
#define HWBAR() { SBAR(); __builtin_amdgcn_s_barrier(); SBAR(); }
#define WAIT_LGKM0() { asm volatile("s_waitcnt lgkmcnt(0)" ::: "memory"); SBAR(); }
#define WAIT_VM(n) { asm volatile("s_waitcnt vmcnt(" #n ")" ::: "memory"); SBAR(); }

// ---------------------------------------------------------------------------
__global__ __launch_bounds__(256)
void absmean_partial(const float* __restrict__ w1, const float* __restrict__ w2,
                     float* __restrict__ part) {
    const int tid = threadIdx.x;
    const int base = blockIdx.x * 3072;
    float s1 = 0.f, s2 = 0.f;
    for (int i = tid; i < 3072; i += 256) {
        s1 += fabsf(w1[base + i]);
        s2 += fabsf(w2[base + i]);
    }
    __shared__ float r1[256], r2[256];
    r1[tid] = s1; r2[tid] = s2;
    __syncthreads();
    for (int off = 128; off > 0; off >>= 1) {
        if (tid < off) { r1[tid] += r1[tid + off]; r2[tid] += r2[tid + off]; }
        __syncthreads();
    }
    if (tid == 0) { part[blockIdx.x] = r1[0]; part[256 + blockIdx.x] = r2[0]; }
}

__global__ __launch_bounds__(256)
void finalize_scale(const float* __restrict__ part, float* __restrict__ sv) {
    const int tid = threadIdx.x;
    __shared__ float r1[256], r2[256];
    r1[tid] = part[tid]; r2[tid] = part[256 + tid];
    __syncthreads();
    for (int off = 128; off > 0; off >>= 1) {
        if (tid < off) { r1[tid] += r1[tid + off]; r2[tid] += r2[tid + off]; }
        __syncthreads();
    }
    if (tid == 0) {
        sv[0] = fmaxf(r1[0] * (1.f / 786432.f), 1e-5f);
        sv[1] = fmaxf(r2[0] * (1.f / 786432.f), 1e-5f);
    }
}

// ---------------------------------------------------------------------------
__global__ __launch_bounds__(256)
void quantize_w(const float* __restrict__ w, const float* __restrict__ sv,
                int sidx, u16* __restrict__ wqt) {
    const int idx = blockIdx.x * 256 + threadIdx.x;
    const float s = sv[sidx];
    float q = rintf(w[idx] / s);
    q = fmaxf(-1.f, fminf(1.f, q));
    const int o   = idx / 1536;
    const int rem = idx - o * 1536;
    const int i   = rem / 3;
    const int k   = rem - i * 3;
    wqt[k * (CCH * CCH) + o * CCH + i] = f2bf(q);
}

__global__ __launch_bounds__(256)
void zero_pads(u16* __restrict__ h, u16* __restrict__ h1) {
    const int idx = blockIdx.x * 256 + threadIdx.x;   // [0, 16384)
    const int b = idx >> 10;
    const int r = (idx >> 9) & 1;
    const int i = idx & 511;
    const size_t off = ((size_t)b * LPAD + (r ? (LPAD - 1) : 0)) * CCH + i;
    h[off] = 0;
    h1[off] = 0;
}

// ---------------------------------------------------------------------------
__global__ __launch_bounds__(256)
void rms_silu_transpose(const float* __restrict__ x, const float* __restrict__ g,
                        u16* __restrict__ h_t) {
    __shared__ u16   xt[CCH][33];
    __shared__ float red[8][32];
    __shared__ float rinv[32];
    const int tid = threadIdx.x;
    const int bb  = blockIdx.x >> 7;
    const int l0  = (blockIdx.x & 127) << 5;

    const size_t xbase = (size_t)bb * CCH * LEN + l0;
    {
        const int i_hi = tid >> 3;
        const int l4   = (tid & 7) << 2;
        #pragma unroll
        for (int it = 0; it < 16; ++it) {
            const int i = it * 32 + i_hi;
            const float4 v = *(const float4*)&x[xbase + (size_t)i * LEN + l4];
            xt[i][l4 + 0] = f2bf(v.x);
            xt[i][l4 + 1] = f2bf(v.y);
            xt[i][l4 + 2] = f2bf(v.z);
            xt[i][l4 + 3] = f2bf(v.w);
        }
    }
    __syncthreads();
    {
        const int l = tid & 31, seg = tid >> 5;
        const int ibeg = seg * 64;
        float ss = 0.f;
        #pragma unroll 8
        for (int i = ibeg; i < ibeg + 64; ++i) {
            const float v = bf2f(xt[i][l]);
            ss += v * v;
        }
        red[seg][l] = ss;
    }
    __syncthreads();
    if (tid < 32) {
        float tot = 0.f;
        #pragma unroll
        for (int k2 = 0; k2 < 8; ++k2) tot += red[k2][tid];
        rinv[tid] = rsqrtf(tot * (1.f / 512.f) + 1e-6f);
    }
    __syncthreads();
    {
        const int l  = tid >> 3;
        const int i0 = (tid & 7) << 6;
        const float ri = rinv[l];
        const size_t ob = ((size_t)bb * LPAD + l0 + l + 1) * CCH + i0;
        for (int ii = 0; ii < 64; ii += 8) {
            u16x8 ov;
            #pragma unroll
            for (int jj = 0; jj < 8; ++jj) {
                const int i = i0 + ii + jj;
                float v = bf2f(xt[i][l]) * ri * g[i];
                ov[jj] = f2bf(silu_f(v));
            }
            *(u16x8*)&h_t[ob + ii] = ov;
        }
    }
}

// ---------------------------------------------------------------------------
// Conv-as-GEMM, 256x256 tile, 1024 threads = 16 waves (4M x 4N), per-wave
// 64x64 (4x4 frags, acc=64 regs -> 4 waves/SIMD for phase diversity).
// BK=64, double-buffered LDS 128 KiB, one barrier per K-step, counted-free
// prefetch (stage t+1 at top of t, vm0 only at step end).  K order ks-inner.
// T1 XCD chunking, T2 XOR swizzle, T5 setprio.
template<int EPI>
__global__ __launch_bounds__(1024)
void conv_gemm8(const u16* __restrict__ Bsrc, const u16* __restrict__ Wq,
                const float* __restrict__ sptr, const float* __restrict__ bias,
                const float* __restrict__ resid, u16* __restrict__ outb,
                float* __restrict__ outf) {
    extern __shared__ u16 lds[];          // 65536 u16 = 128 KiB
    const int tid  = threadIdx.x;
    const int lane = tid & 63;
    const int wave = tid >> 6;
    const int wm = wave >> 2;             // 0..3  (M quarter: rows wm*64..)
    const int wn = wave & 3;              // 0..3  (N quarter)

    // T1: bijective XCD chunking (512 = 8 x 64); mt-pairs share a B-panel.
    const int wgid = (blockIdx.x & 7) * 64 + (blockIdx.x >> 3);
    const int mt = wgid & 1;
    const int nt = wgid >> 1;
    const int o0 = mt << 8;
    const int bb = nt >> 4;
    const int l0 = (nt & 15) << 8;

    // staging: 1024 threads; row = j*128 + (tid>>3); col chunk = (tid&7)*8 u16
    const int sr  = tid >> 3;                              // 0..127
    const int scu = ((tid & 7) << 3) ^ ((sr & 7) << 3);    // pre-swizzled src col
    const int sdst = tid << 3;                             // u16 in 8192-u16 chunk

    const u16* aSrcBase = Wq + (size_t)o0 * CCH + scu;
    const u16* bSrcBase = Bsrc + ((size_t)bb * LPAD + l0) * CCH + scu;

    // stage full K-step tile (A 256x64 + B 256x64) into buf pb: 4 async16
    auto stage_full = [&](int pb, int ks2, int i02) {
        #pragma unroll
        for (int j = 0; j < 2; ++j) {
            const int r = j * 128 + sr;
            async16(aSrcBase + ks2 * (CCH * CCH) + r * CCH + i02,
                    &lds[pb * 32768 + j * 8192 + sdst]);
            async16(bSrcBase + (size_t)(r + ks2) * CCH + i02,
                    &lds[pb * 32768 + 16384 + j * 8192 + sdst]);
        }
    };

    // ds_read geometry (swizzled).  kk=0 cols 0..31, kk=1 cols 32..63.
    const int swz = (lane & 7) << 3;
    const int c0 = ((lane >> 4) << 3) ^ swz;
    const int c1 = (((lane >> 4) << 3) + 32) ^ swz;
    const int aB = wm * 4096 + (lane & 15) * 64;           // A region base (u16)
    const int bB = 16384 + wn * 4096 + (lane & 15) * 64;   // B region base

    f32x4 acc[4][4];
    #pragma unroll
    for (int m = 0; m < 4; ++m)
        #pragma unroll
        for (int n = 0; n < 4; ++n)
            acc[m][n] = (f32x4){0.f, 0.f, 0.f, 0.f};

    // prologue: tile 0 -> buf0
    stage_full(0, 0, 0);
    WAIT_VM(0);
    HWBAR();

    for (int t = 0; t < 24; ++t) {
        const int cur = t & 1;
        const int cbase = cur * 32768;
        if (t + 1 < 24) {
            const int tn = t + 1;
            stage_full(cur ^ 1, tn % 3, (tn / 3) << 6);   // prefetch next tile
        }
        #pragma unroll
        for (int kk = 0; kk < 2; ++kk) {
            const int ck = kk ? c1 : c0;
            bf16x8 ar[4], br[4];
            #pragma unroll
            for (int m = 0; m < 4; ++m)
                ar[m] = *(const bf16x8*)&lds[cbase + aB + m * 1024 + ck];
            #pragma unroll
            for (int n = 0; n < 4; ++n)
                br[n] = *(const bf16x8*)&lds[cbase + bB + n * 1024 + ck];
            __builtin_amdgcn_s_setprio(1);
            #pragma unroll
            for (int m = 0; m < 4; ++m)
                #pragma unroll
                for (int n = 0; n < 4; ++n)
                    acc[m][n] = __builtin_amdgcn_mfma_f32_16x16x32_bf16(
                        ar[m], br[n], acc[m][n], 0, 0, 0);
            __builtin_amdgcn_s_setprio(0);
        }
        WAIT_LGKM0();                  // reads of buf[cur] retired (WAR safety)
        WAIT_VM(0);                    // next tile landed
        HWBAR();
    }

    // epilogue
    const float sc = sptr[0];

    if (EPI == 1) {
        // silu(sc*acc+bias) -> LDS [l_loc 0..255][o_loc 0..255] bf16 (swizzled),
        // then coalesced 16B stores (4 lanes fill one 64B sector).
        #pragma unroll
        for (int m = 0; m < 4; ++m) {
            const int o_loc = wm * 64 + m * 16 + ((lane >> 4) << 2);
            const int ob = o0 + o_loc;
            const float b0 = bias[ob + 0], b1 = bias[ob + 1];
            const float b2 = bias[ob + 2], b3 = bias[ob + 3];
            #pragma unroll
            for (int n = 0; n < 4; ++n) {
                const int l_loc = wn * 64 + n * 16 + (lane & 15);
                const f32x4 a = acc[m][n];
                u16x4 ov;
                ov[0] = f2bf(silu_f(sc * a[0] + b0));
                ov[1] = f2bf(silu_f(sc * a[1] + b1));
                ov[2] = f2bf(silu_f(sc * a[2] + b2));
                ov[3] = f2bf(silu_f(sc * a[3] + b3));
                char* p = (char*)lds + l_loc * 512 +
                          (((unsigned)(o_loc << 1)) ^ ((l_loc & 7) << 4));
                *(u16x4*)p = ov;
            }
        }
        __syncthreads();
        const int l_r = tid >> 2;            // 0..255
        const int oq  = (tid & 3) << 3;      // u16: 0,8,16,24
        u16* gdst = outb + ((size_t)bb * LPAD + l0 + l_r + 1) * CCH + o0 + oq;
        char* srp = (char*)lds + l_r * 512;
        const int swz2 = (l_r & 7) << 4;
        #pragma unroll
        for (int c = 0; c < 8; ++c) {
            const uint4 v = *(const uint4*)(srp + (((oq << 1) + c * 64) ^ swz2));
            *(uint4*)(gdst + c * 32) = v;
        }
    } else {
        const int lbase = l0 + wn * 64 + (lane & 15);
        const int obase = o0 + wm * 64 + ((lane >> 4) << 2);
        #pragma unroll
        for (int m = 0; m < 4; ++m) {
            const int ob = obase + m * 16;
            #pragma unroll
            for (int n = 0; n < 4; ++n) {
                const int l = lbase + n * 16;
                const f32x4 a = acc[m][n];
                #pragma unroll
                for (int jj = 0; jj < 4; ++jj) {
                    const size_t idx = ((size_t)bb * CCH + (ob + jj)) * LEN + l;
                    outf[idx] = sc * a[jj] + bias[ob + jj] + resid[idx];
                }
            }
        }
    }
}

// ---------------------------------------------------------------------------
extern "C" void kernel_launch(void* const* d_in, const int* in_sizes, int n_in,
                              void* d_out, int out_size, void* d_ws, size_t ws_size,
                              hipStream_t stream) {
    const float* x  = (const float*)d_in[0];
    const float* w1 = (const float*)d_in[1];
    const float* b1 = (const float*)d_in[2];
    const float* w2 = (const float*)d_in[3];
    const float* b2 = (const float*)d_in[4];
    const float* g  = (const float*)d_in[5];
    float* out = (float*)d_out;

    char* ws = (char*)d_ws;
    float* sv   = (float*)ws;
    float* part = (float*)(ws + 256);
    u16* wq1   = (u16*)(ws + 4096);
    u16* wq2   = (u16*)(ws + 4096 + 1572864);
    u16* h_t   = (u16*)(ws + 4096 + 2 * 1572864);                 // [16][4098][512] bf16
    u16* h1_t  = (u16*)(ws + 4096 + 2 * 1572864 + 67141632);      // [16][4098][512] bf16

    hipFuncSetAttribute((const void*)conv_gemm8<1>,
                        hipFuncAttributeMaxDynamicSharedMemorySize, 131072);
    hipFuncSetAttribute((const void*)conv_gemm8<2>,
                        hipFuncAttributeMaxDynamicSharedMemorySize, 131072);

    absmean_partial<<<dim3(256), dim3(256), 0, stream>>>(w1, w2, part);
    finalize_scale<<<dim3(1), dim3(256), 0, stream>>>(part, sv);
    quantize_w<<<dim3(3072), dim3(256), 0, stream>>>(w1, sv, 0, wq1);
    quantize_w<<<dim3(3072), dim3(256), 0, stream>>>(w2, sv, 1, wq2);
    zero_pads<<<dim3(64), dim3(256), 0, stream>>>(h_t, h1_t);
    rms_silu_transpose<<<dim3(2048), dim3(256), 0, stream>>>(x, g, h_t);
    conv_gemm8<1><<<dim3(512), dim3(1024), 131072, stream>>>(h_t, wq1, sv, b1,
                                                             nullptr, h1_t, nullptr);
    conv_gemm8<2><<<dim3(512), dim3(1024), 131072, stream>>>(h1_t, wq2, sv + 1, b2,
                                                             x, nullptr, out);
}